// Round 1
// baseline (276.232 us; speedup 1.0000x reference)
//
#include <hip/hip_runtime.h>

// ---------- types ----------
typedef __attribute__((ext_vector_type(8))) short bf16x8;   // 8 bf16 (4 VGPRs)
typedef __attribute__((ext_vector_type(4))) float f32x4;

__device__ __forceinline__ unsigned short f2bf(float f) {
    unsigned int u = __float_as_uint(f);
    unsigned int r = (u + 0x7fffu + ((u >> 16) & 1u)) >> 16;   // RNE
    return (unsigned short)r;
}

// Problem constants
// x: (8,1024,64,64) f32; W: (1024,1049) f32; b: (1024,)
// out: (8,1024,64,64) f32
// M = 32768 (b*4096 + y*64 + x), K = 1049 -> pad 1056, N = 1024
#define KPAD 1056

// ---------- kernel: W (1024,1049) f32 -> Wb[n][k] bf16, k padded to 1056 ----------
__global__ void kWb_conv(const float* __restrict__ W, unsigned short* __restrict__ Wb)
{
    const int o = blockIdx.x;
    for (int k = threadIdx.x; k < KPAD; k += 256) {
        float v = (k < 1049) ? W[(size_t)o * 1049 + k] : 0.f;
        Wb[(size_t)o * KPAD + k] = f2bf(v);
    }
}

// ---------- kernel: transpose+convert x -> xT[m][k] bf16 (k<1024 region) ----------
// block: 64 m x 128 c; thread: 4 m x 8 c register transpose
__global__ void kT_conv(const float* __restrict__ x, unsigned short* __restrict__ xT)
{
    const int bid = blockIdx.x;          // 4096 = 512 mtiles * 8 ctiles
    const int mst = bid >> 3;
    const int ct  = bid & 7;
    const int m0  = mst * 64;
    const int b   = m0 >> 12, ms0 = m0 & 4095;
    const int t   = threadIdx.x;
    const int msq = (t & 15) * 4;
    const int c0  = ct * 128 + (t >> 4) * 8;

    const float* src = x + ((size_t)b * 1024 + c0) * 4096 + ms0 + msq;
    float4 v[8];
    #pragma unroll
    for (int j = 0; j < 8; ++j)
        v[j] = *(const float4*)(src + (size_t)j * 4096);

    #pragma unroll
    for (int p = 0; p < 4; ++p) {
        unsigned int w[4];
        #pragma unroll
        for (int q = 0; q < 4; ++q) {
            float lo = ((const float*)&v[2 * q])[p];
            float hi = ((const float*)&v[2 * q + 1])[p];
            w[q] = (unsigned int)f2bf(lo) | ((unsigned int)f2bf(hi) << 16);
        }
        *(uint4*)((char*)xT + (size_t)(m0 + msq + p) * (KPAD * 2) + c0 * 2) =
            make_uint4(w[0], w[1], w[2], w[3]);
    }
}

// ---------- kernel: local self-correlation partials ----------
// grid 512 = split(16) * b(8) * rowgroup(4: 16 rows). 256 thr: 16 rows x 16 col-strips(P=4)
// 64 channels per block, f32 LDS slab [20 rows][68 cols], slab col = image col + 2
__global__ __launch_bounds__(256) void k1a_corr(const float* __restrict__ x,
                                                float* __restrict__ fpart)
{
    __shared__ float slab[2][20][68];
    const int bid   = blockIdx.x;
    const int split = bid & 15;
    const int b     = (bid >> 4) & 7;
    const int rg    = bid >> 7;
    const int y0    = rg * 16;
    const int t     = threadIdx.x;
    const int tc    = t & 15, tr = t >> 4;
    const int cs    = tc * 4;

    // zero halo cols (image cols -2,-1,64,65) once; staging never touches them
    if (t < 160) {
        int buf = t / 80, rem = t % 80;
        int r = rem >> 2, cc = rem & 3;
        slab[buf][r][(cc < 2) ? cc : (64 + cc)] = 0.f;
    }

    float acc[25][4];
    #pragma unroll
    for (int s = 0; s < 25; ++s)
        #pragma unroll
        for (int p = 0; p < 4; ++p) acc[s][p] = 0.f;

    const float* xb = x + ((size_t)b * 1024 + split * 64) * 4096;

    auto stage = [&](int i, int buf) {
        const float* src = xb + (size_t)i * 4096;
        #pragma unroll
        for (int pass = 0; pass < 2; ++pass) {
            int idx = t + pass * 256;
            if (idx < 320) {
                int r = idx >> 4, c4 = idx & 15;
                int y = y0 - 2 + r;
                float4 v = make_float4(0.f, 0.f, 0.f, 0.f);
                if (y >= 0 && y < 64) v = *(const float4*)(src + y * 64 + c4 * 4);
                float2* dst = (float2*)&slab[buf][r][2 + c4 * 4];   // 8B aligned
                dst[0] = make_float2(v.x, v.y);
                dst[1] = make_float2(v.z, v.w);
            }
        }
    };

    stage(0, 0);
    for (int i = 0; i < 64; ++i) {
        __syncthreads();
        if (i + 1 < 64) stage(i + 1, (i + 1) & 1);
        const int buf = i & 1;
        const float* base = &slab[buf][tr][cs];

        float ctr[4], wf[8];
        // row r=2 first (centers, dy=0)
        {
            const float4* pr = (const float4*)(base + 2 * 68);
            float4 a = pr[0], b4 = pr[1];
            wf[0]=a.x; wf[1]=a.y; wf[2]=a.z; wf[3]=a.w;
            wf[4]=b4.x; wf[5]=b4.y; wf[6]=b4.z; wf[7]=b4.w;
            ctr[0]=wf[2]; ctr[1]=wf[3]; ctr[2]=wf[4]; ctr[3]=wf[5];
            #pragma unroll
            for (int dx = -2; dx <= 2; ++dx)
                #pragma unroll
                for (int p = 0; p < 4; ++p)
                    acc[10 + dx + 2][p] += wf[p + 2 + dx] * ctr[p];
        }
        #pragma unroll
        for (int r = 0; r < 5; ++r) {
            if (r == 2) continue;
            const float4* pr = (const float4*)(base + r * 68);
            float4 a = pr[0], b4 = pr[1];
            wf[0]=a.x; wf[1]=a.y; wf[2]=a.z; wf[3]=a.w;
            wf[4]=b4.x; wf[5]=b4.y; wf[6]=b4.z; wf[7]=b4.w;
            #pragma unroll
            for (int dx = -2; dx <= 2; ++dx)
                #pragma unroll
                for (int p = 0; p < 4; ++p)
                    acc[r * 5 + dx + 2][p] += wf[p + 2 + dx] * ctr[p];
        }
    }

    const int mbase = b * 4096 + (y0 + tr) * 64 + cs;
    #pragma unroll
    for (int s = 0; s < 25; ++s) {
        *(float4*)(fpart + (size_t)(split * 25 + s) * 32768 + mbase) =
            make_float4(acc[s][0], acc[s][1], acc[s][2], acc[s][3]);
    }
}

// ---------- kernel: reduce 16 partials, L2-normalize, write bf16 into xT[m][1024..1056) ----------
__global__ void k1b_norm(const float* __restrict__ fpart, unsigned short* __restrict__ xT)
{
    const int m = blockIdx.x * 256 + threadIdx.x;
    float f[25];
    #pragma unroll
    for (int s = 0; s < 25; ++s) {
        float v = 0.f;
        #pragma unroll
        for (int sp = 0; sp < 16; ++sp)
            v += fpart[(size_t)(sp * 25 + s) * 32768 + m];
        f[s] = v;
    }
    float ss = 1e-6f;
    #pragma unroll
    for (int s = 0; s < 25; ++s) ss += f[s] * f[s];
    const float inv = 1.f / sqrtf(ss);

    unsigned int w[16];
    #pragma unroll
    for (int q = 0; q < 16; ++q) w[q] = 0u;
    #pragma unroll
    for (int s = 0; s < 25; ++s) {
        unsigned int h = f2bf(f[s] * inv);
        w[s >> 1] |= h << ((s & 1) * 16);
    }
    uint4* dst = (uint4*)((char*)xT + (size_t)m * (KPAD * 2) + 2048);
    dst[0] = make_uint4(w[0],  w[1],  w[2],  w[3]);
    dst[1] = make_uint4(w[4],  w[5],  w[6],  w[7]);
    dst[2] = make_uint4(w[8],  w[9],  w[10], w[11]);
    dst[3] = make_uint4(w[12], w[13], w[14], w[15]);
}

// ---------- kernel: GEMM out[m][n] = relu( sum_k xT[m][k]*Wb[n][k] + bias[n] ) ----------
// m97 structure: BM=BN=128, BK=32, 4 waves (2x2 of 64x64), 16x16x32 bf16 MFMA,
// global_load_lds width 16, both-sides XOR unit swizzle, XCD-chunked grid swizzle.
__global__ __launch_bounds__(256) void kgemm(const unsigned short* __restrict__ xT,
                                             const unsigned short* __restrict__ Wb,
                                             const float* __restrict__ bias,
                                             float* __restrict__ out)
{
    __shared__ unsigned short As[128 * 32];
    __shared__ unsigned short Bs[128 * 32];

    const int bid = blockIdx.x;                    // 2048
    const int wg  = (bid & 7) * 256 + (bid >> 3);  // XCD chunk swizzle (bijective)
    const int mt  = wg >> 3, nt = wg & 7;
    const int m0  = mt * 128, n0 = nt * 128;
    const int t   = threadIdx.x;
    const int l   = t & 63, w = t >> 6;
    const int lr  = l & 15;
    const int wm  = w >> 1, wn = w & 1;

    // staging lane geometry: dest = linear (row=l>>2, slot=l&3); source pre-swizzled
    const int sr = l >> 2;
    const int su = (l & 3) ^ (sr & 3);
    // read-side swizzle in ushort units: phys slot = kq ^ (row&3), row&3 == l&3
    const int swz = (((l >> 4) ^ (l & 3)) << 3);

    f32x4 zero = {0.f, 0.f, 0.f, 0.f};
    f32x4 acc[4][4];
    #pragma unroll
    for (int i = 0; i < 4; ++i)
        #pragma unroll
        for (int j = 0; j < 4; ++j) acc[i][j] = zero;

    for (int kk = 0; kk < 33; ++kk) {
        #pragma unroll
        for (int q = 0; q < 2; ++q) {
            const int rb = w * 32 + q * 16;
            const unsigned short* ga = xT + (size_t)(m0 + rb + sr) * KPAD + kk * 32 + su * 8;
            const unsigned short* gb = Wb + (size_t)(n0 + rb + sr) * KPAD + kk * 32 + su * 8;
            __builtin_amdgcn_global_load_lds((const void*)ga, (void*)&As[rb * 32], 16, 0, 0);
            __builtin_amdgcn_global_load_lds((const void*)gb, (void*)&Bs[rb * 32], 16, 0, 0);
        }
        asm volatile("s_waitcnt vmcnt(0)" ::: "memory");
        __syncthreads();

        bf16x8 af[4], bf[4];
        #pragma unroll
        for (int i = 0; i < 4; ++i) {
            af[i] = *(const bf16x8*)&As[(wm * 64 + i * 16 + lr) * 32 + swz];
            bf[i] = *(const bf16x8*)&Bs[(wn * 64 + i * 16 + lr) * 32 + swz];
        }
        #pragma unroll
        for (int i = 0; i < 4; ++i)
            #pragma unroll
            for (int j = 0; j < 4; ++j)
                acc[i][j] = __builtin_amdgcn_mfma_f32_16x16x32_bf16(af[i], bf[j], acc[i][j], 0, 0, 0);
        __syncthreads();
    }

    // epilogue: D col = lane&15 (n), row = (lane>>4)*4 + reg (m)
    const int bb    = m0 >> 12;
    const int mloc0 = (m0 & 4095) + wm * 64 + (l >> 4) * 4;
    #pragma unroll
    for (int j = 0; j < 4; ++j) {
        const int n = n0 + wn * 64 + j * 16 + lr;
        const float bv = bias[n];
        float* obase = out + (size_t)bb * 4194304 + (size_t)n * 4096;
        #pragma unroll
        for (int i = 0; i < 4; ++i) {
            f32x4 v = acc[i][j];
            float4 o = make_float4(fmaxf(v[0] + bv, 0.f), fmaxf(v[1] + bv, 0.f),
                                   fmaxf(v[2] + bv, 0.f), fmaxf(v[3] + bv, 0.f));
            *(float4*)(obase + mloc0 + i * 16) = o;
        }
    }
}

// ---------- launch ----------
extern "C" void kernel_launch(void* const* d_in, const int* in_sizes, int n_in,
                              void* d_out, int out_size, void* d_ws, size_t ws_size,
                              hipStream_t stream)
{
    const float* x    = (const float*)d_in[0];
    const float* W    = (const float*)d_in[1];
    const float* bias = (const float*)d_in[2];
    float* out        = (float*)d_out;

    char* ws = (char*)d_ws;
    // xT: 32768*1056*2 = 69,206,016 B ; Wb: 1056*1024*2 = 2,162,688 B ; fpart: 16*25*32768*4 = 52,428,800 B
    unsigned short* xT = (unsigned short*)ws;
    unsigned short* Wb = (unsigned short*)(ws + 69206016);
    float* fpart       = (float*)(ws + 71368704);

    kWb_conv<<<1024, 256, 0, stream>>>(W, Wb);
    kT_conv <<<4096, 256, 0, stream>>>(x, xT);
    k1a_corr<<<512,  256, 0, stream>>>(x, fpart);
    k1b_norm<<<128,  256, 0, stream>>>(fpart, xT);
    kgemm   <<<2048, 256, 0, stream>>>(xT, Wb, bias, out);
}

// Round 2
// 273.468 us; speedup vs baseline: 1.0101x; 1.0101x over previous
//
#include <hip/hip_runtime.h>

// ---------- types ----------
typedef __attribute__((ext_vector_type(8))) short bf16x8;   // 8 bf16 (4 VGPRs)
typedef __attribute__((ext_vector_type(4))) float f32x4;

__device__ __forceinline__ unsigned short f2bf(float f) {
    unsigned int u = __float_as_uint(f);
    unsigned int r = (u + 0x7fffu + ((u >> 16) & 1u)) >> 16;   // RNE
    return (unsigned short)r;
}

// Problem constants
// x: (8,1024,64,64) f32; W: (1024,1049) f32; b: (1024,)
// out: (8,1024,64,64) f32
// M = 32768, K = 1049 -> pad 1088 (17 K-tiles of 64), N = 1024
#define KPAD 1088
#define NT   17

// ---------- kernel: W (1024,1049) f32 -> Wb[n][k] bf16, k padded to 1088 ----------
__global__ void kWb_conv(const float* __restrict__ W, unsigned short* __restrict__ Wb)
{
    const int o = blockIdx.x;
    for (int k = threadIdx.x; k < KPAD; k += 256) {
        float v = (k < 1049) ? W[(size_t)o * 1049 + k] : 0.f;
        Wb[(size_t)o * KPAD + k] = f2bf(v);
    }
}

// ---------- kernel: transpose+convert x -> xT[m][k] bf16 (k<1024 region) ----------
// block: 64 m x 128 c. Register 4x4 transpose -> LDS (chunk-XOR swizzle) -> coalesced writes.
__global__ __launch_bounds__(256) void kT_conv(const float* __restrict__ x,
                                               unsigned short* __restrict__ xT)
{
    __shared__ unsigned short tile[64][128];   // 16KB; 16 chunks of 16B per row, XOR-swizzled
    const int bid = blockIdx.x;          // 4096 = 512 mtiles * 8 ctiles
    const int mst = bid >> 3;
    const int ct  = bid & 7;
    const int m0  = mst * 64;
    const int b   = m0 >> 12, ms0 = m0 & 4095;
    const int t   = threadIdx.x;
    const int msq = (t & 15) * 4;        // m offset 0..60
    const int cg  = t >> 4;              // 0..15 channel-group (8 ch)
    const int c0  = ct * 128 + cg * 8;

    const float* src = x + ((size_t)b * 1024 + c0) * 4096 + ms0 + msq;
    float4 v[8];
    #pragma unroll
    for (int j = 0; j < 8; ++j)
        v[j] = *(const float4*)(src + (size_t)j * 4096);

    #pragma unroll
    for (int p = 0; p < 4; ++p) {
        unsigned int w[4];
        #pragma unroll
        for (int q = 0; q < 4; ++q) {
            float lo = ((const float*)&v[2 * q])[p];
            float hi = ((const float*)&v[2 * q + 1])[p];
            w[q] = (unsigned int)f2bf(lo) | ((unsigned int)f2bf(hi) << 16);
        }
        const int row = msq + p;
        const int pch = cg ^ ((row >> 2) & 15);      // swizzle (involution)
        *(uint4*)&tile[row][pch * 8] = make_uint4(w[0], w[1], w[2], w[3]);
    }
    __syncthreads();

    #pragma unroll
    for (int q = 0; q < 4; ++q) {
        const int flat = q * 256 + t;                // 0..1023
        const int row  = flat >> 4, ch = flat & 15;
        const int pch  = ch ^ ((row >> 2) & 15);
        uint4 val = *(const uint4*)&tile[row][pch * 8];
        *(uint4*)((char*)xT + (size_t)(m0 + row) * (KPAD * 2) + (size_t)(ct * 128 + ch * 8) * 2) = val;
    }
}

// ---------- kernel: local self-correlation partials ----------
// grid 256 = split(8) * b(8) * rowgroup(4: 16 rows). 256 thr: 16 rows x 16 col-strips(P=4)
// 128 channels per block, f32 LDS slab [20 rows][68 cols], slab col = image col + 2
__global__ __launch_bounds__(256) void k1a_corr(const float* __restrict__ x,
                                                float* __restrict__ fpart)
{
    __shared__ float slab[2][20][68];
    const int bid   = blockIdx.x;
    const int split = bid & 7;
    const int b     = (bid >> 3) & 7;
    const int rg    = bid >> 6;
    const int y0    = rg * 16;
    const int t     = threadIdx.x;
    const int tc    = t & 15, tr = t >> 4;
    const int cs    = tc * 4;

    if (t < 160) {
        int buf = t / 80, rem = t % 80;
        int r = rem >> 2, cc = rem & 3;
        slab[buf][r][(cc < 2) ? cc : (64 + cc)] = 0.f;
    }

    float acc[25][4];
    #pragma unroll
    for (int s = 0; s < 25; ++s)
        #pragma unroll
        for (int p = 0; p < 4; ++p) acc[s][p] = 0.f;

    const float* xb = x + ((size_t)b * 1024 + split * 128) * 4096;

    auto stage = [&](int i, int buf) {
        const float* src = xb + (size_t)i * 4096;
        #pragma unroll
        for (int pass = 0; pass < 2; ++pass) {
            int idx = t + pass * 256;
            if (idx < 320) {
                int r = idx >> 4, c4 = idx & 15;
                int y = y0 - 2 + r;
                float4 v = make_float4(0.f, 0.f, 0.f, 0.f);
                if (y >= 0 && y < 64) v = *(const float4*)(src + y * 64 + c4 * 4);
                float2* dst = (float2*)&slab[buf][r][2 + c4 * 4];
                dst[0] = make_float2(v.x, v.y);
                dst[1] = make_float2(v.z, v.w);
            }
        }
    };

    stage(0, 0);
    for (int i = 0; i < 128; ++i) {
        __syncthreads();
        if (i + 1 < 128) stage(i + 1, (i + 1) & 1);
        const int buf = i & 1;
        const float* base = &slab[buf][tr][cs];

        float ctr[4], wf[8];
        {
            const float4* pr = (const float4*)(base + 2 * 68);
            float4 a = pr[0], b4 = pr[1];
            wf[0]=a.x; wf[1]=a.y; wf[2]=a.z; wf[3]=a.w;
            wf[4]=b4.x; wf[5]=b4.y; wf[6]=b4.z; wf[7]=b4.w;
            ctr[0]=wf[2]; ctr[1]=wf[3]; ctr[2]=wf[4]; ctr[3]=wf[5];
            #pragma unroll
            for (int dx = -2; dx <= 2; ++dx)
                #pragma unroll
                for (int p = 0; p < 4; ++p)
                    acc[10 + dx + 2][p] += wf[p + 2 + dx] * ctr[p];
        }
        #pragma unroll
        for (int r = 0; r < 5; ++r) {
            if (r == 2) continue;
            const float4* pr = (const float4*)(base + r * 68);
            float4 a = pr[0], b4 = pr[1];
            wf[0]=a.x; wf[1]=a.y; wf[2]=a.z; wf[3]=a.w;
            wf[4]=b4.x; wf[5]=b4.y; wf[6]=b4.z; wf[7]=b4.w;
            #pragma unroll
            for (int dx = -2; dx <= 2; ++dx)
                #pragma unroll
                for (int p = 0; p < 4; ++p)
                    acc[r * 5 + dx + 2][p] += wf[p + 2 + dx] * ctr[p];
        }
    }

    const int mbase = b * 4096 + (y0 + tr) * 64 + cs;
    #pragma unroll
    for (int s = 0; s < 25; ++s) {
        *(float4*)(fpart + (size_t)(split * 25 + s) * 32768 + mbase) =
            make_float4(acc[s][0], acc[s][1], acc[s][2], acc[s][3]);
    }
}

// ---------- kernel: reduce 8 partials, L2-normalize, write bf16 into xT[m][1024..1088) ----------
__global__ void k1b_norm(const float* __restrict__ fpart, unsigned short* __restrict__ xT)
{
    const int m = blockIdx.x * 256 + threadIdx.x;
    float f[25];
    #pragma unroll
    for (int s = 0; s < 25; ++s) {
        float v = 0.f;
        #pragma unroll
        for (int sp = 0; sp < 8; ++sp)
            v += fpart[(size_t)(sp * 25 + s) * 32768 + m];
        f[s] = v;
    }
    float ss = 1e-6f;
    #pragma unroll
    for (int s = 0; s < 25; ++s) ss += f[s] * f[s];
    const float inv = 1.f / sqrtf(ss);

    unsigned int w[16];
    #pragma unroll
    for (int q = 0; q < 16; ++q) w[q] = 0u;
    #pragma unroll
    for (int s = 0; s < 25; ++s) {
        unsigned int h = f2bf(f[s] * inv);
        w[s >> 1] |= h << ((s & 1) * 16);
    }
    uint4* dst = (uint4*)((char*)xT + (size_t)m * (KPAD * 2) + 2048);
    dst[0] = make_uint4(w[0],  w[1],  w[2],  w[3]);
    dst[1] = make_uint4(w[4],  w[5],  w[6],  w[7]);
    dst[2] = make_uint4(w[8],  w[9],  w[10], w[11]);
    dst[3] = make_uint4(w[12], w[13], w[14], w[15]);
    uint4 z = make_uint4(0u, 0u, 0u, 0u);
    dst[4] = z; dst[5] = z; dst[6] = z; dst[7] = z;   // pad 1056..1088 = 0
}

// ---------- kernel: 256x256 8-phase GEMM, out = relu(xT @ Wb^T + bias) ----------
// BM=BN=256, BK=64, 8 waves (2M x 4N), per-wave 128x64, 16x16x32 bf16 MFMA.
// LDS 128KB: A/B double-buffered [2][256][64] bf16 with 8-slot XOR swizzle.
// Counted vmcnt(4) pipeline: stage {ph1:Alo(t+1), ph2:Ahi(t+1), ph3:Blo(t+2), ph4:Bhi(t+2)}.
__global__ __launch_bounds__(512, 2) void kgemm(const unsigned short* __restrict__ xT,
                                                const unsigned short* __restrict__ Wb,
                                                const float* __restrict__ bias,
                                                float* __restrict__ out)
{
    __shared__ unsigned short LA[2][256][64];   // 64KB
    __shared__ unsigned short LB[2][256][64];   // 64KB

    const int bid = blockIdx.x;                 // 512 blocks
    const int wg  = (bid & 7) * 64 + (bid >> 3);// XCD chunk swizzle (512 % 8 == 0, bijective)
    const int mt  = wg >> 2, nt = wg & 3;
    const int m0  = mt * 256, n0 = nt * 256;
    const int t   = threadIdx.x;
    const int l   = t & 63, w = t >> 6;
    const int lr  = l & 15, kq = l >> 4;
    const int wm  = w >> 2, wn = w & 3;

    // staging geometry: lane writes phys 16B chunk (row = w*8 + (l>>3), slot = l&7);
    // source fetches logical slot (l&7) ^ (l>>3)  -> read-side XOR undoes it.
    const int sr = l >> 3;
    const int sp = (l & 7) ^ sr;
    const unsigned short* gA = xT + (size_t)(m0 + w * 8 + sr) * KPAD + sp * 8;
    const unsigned short* gB = Wb + (size_t)(n0 + w * 8 + sr) * KPAD + sp * 8;

    // half: 0 = A rows[0:128), 1 = A[128:256), 2 = B[0:128), 3 = B[128:256)
    auto STAGE = [&](int tt, int half) {
        if ((unsigned)tt >= NT) return;
        const int db = tt & 1;
        const size_t ko = (size_t)tt * 64;
        if (half < 2) {
            const unsigned short* g = gA + (size_t)(half * 128) * KPAD + ko;
            __builtin_amdgcn_global_load_lds((const void*)g,
                (void*)&LA[db][half * 128 + w * 8][0], 16, 0, 0);
            __builtin_amdgcn_global_load_lds((const void*)(g + (size_t)64 * KPAD),
                (void*)&LA[db][half * 128 + 64 + w * 8][0], 16, 0, 0);
        } else {
            const int hb = half - 2;
            const unsigned short* g = gB + (size_t)(hb * 128) * KPAD + ko;
            __builtin_amdgcn_global_load_lds((const void*)g,
                (void*)&LB[db][hb * 128 + w * 8][0], 16, 0, 0);
            __builtin_amdgcn_global_load_lds((const void*)(g + (size_t)64 * KPAD),
                (void*)&LB[db][hb * 128 + 64 + w * 8][0], 16, 0, 0);
        }
    };

    f32x4 zero = {0.f, 0.f, 0.f, 0.f};
    f32x4 acc[8][4];
    #pragma unroll
    for (int i = 0; i < 8; ++i)
        #pragma unroll
        for (int j = 0; j < 4; ++j) acc[i][j] = zero;

    bf16x8 a0[4][2], a1[4][2], b0[2][2], b1[2][2];

    #define LDA(dst, db, ih)                                                     \
        _Pragma("unroll")                                                        \
        for (int i = 0; i < 4; ++i) {                                            \
            _Pragma("unroll")                                                    \
            for (int ks = 0; ks < 2; ++ks) {                                     \
                const int row = wm * 128 + ((ih) * 4 + i) * 16 + lr;             \
                const int slot = (ks * 4 + kq) ^ (row & 7);                      \
                dst[i][ks] = *(const bf16x8*)&LA[db][row][slot * 8];             \
            }                                                                    \
        }
    #define LDB(dst, db, jh)                                                     \
        _Pragma("unroll")                                                        \
        for (int j = 0; j < 2; ++j) {                                            \
            _Pragma("unroll")                                                    \
            for (int ks = 0; ks < 2; ++ks) {                                     \
                const int row = wn * 64 + ((jh) * 2 + j) * 16 + lr;              \
                const int slot = (ks * 4 + kq) ^ (row & 7);                      \
                dst[j][ks] = *(const bf16x8*)&LB[db][row][slot * 8];             \
            }                                                                    \
        }
    #define MM(A, B, i0, j0)                                                     \
        _Pragma("unroll")                                                        \
        for (int ks = 0; ks < 2; ++ks) {                                         \
            _Pragma("unroll")                                                    \
            for (int i = 0; i < 4; ++i) {                                        \
                _Pragma("unroll")                                                \
                for (int j = 0; j < 2; ++j)                                      \
                    acc[(i0) + i][(j0) + j] = __builtin_amdgcn_mfma_f32_16x16x32_bf16( \
                        A[i][ks], B[j][ks], acc[(i0) + i][(j0) + j], 0, 0, 0);   \
            }                                                                    \
        }
    #define PH_OPEN()                                                            \
        asm volatile("s_barrier" ::: "memory");                                  \
        asm volatile("s_waitcnt lgkmcnt(0)" ::: "memory");                       \
        __builtin_amdgcn_sched_barrier(0);                                       \
        __builtin_amdgcn_s_setprio(1);
    #define PH_CLOSE()                                                           \
        __builtin_amdgcn_s_setprio(0);                                           \
        asm volatile("s_barrier" ::: "memory");

    // prologue: tile 0 complete + B halves of tile 1 in flight
    STAGE(0, 0); STAGE(0, 1); STAGE(0, 2); STAGE(0, 3);
    STAGE(1, 2); STAGE(1, 3);
    asm volatile("s_waitcnt vmcnt(4)" ::: "memory");
    asm volatile("s_barrier" ::: "memory");

    for (int tt = 0; tt < NT; ++tt) {
        const int db = tt & 1;
        // ---- phase 1: read A-frags 0..3 + B-frags 0..1; stage A-lo(t+1); MFMA q(0,0)
        LDA(a0, db, 0)
        LDB(b0, db, 0)
        STAGE(tt + 1, 0);
        PH_OPEN()
        MM(a0, b0, 0, 0)
        PH_CLOSE()
        // ---- phase 2: read B-frags 2..3; stage A-hi(t+1); MFMA q(0,1)
        LDB(b1, db, 1)
        STAGE(tt + 1, 1);
        PH_OPEN()
        MM(a0, b1, 0, 2)
        PH_CLOSE()
        // ---- phase 3: read A-frags 4..7; stage B-lo(t+2); MFMA q(1,1)
        LDA(a1, db, 1)
        STAGE(tt + 2, 2);
        PH_OPEN()
        MM(a1, b1, 4, 2)
        PH_CLOSE()
        // ---- phase 4: stage B-hi(t+2); MFMA q(1,0); boundary vmcnt
        STAGE(tt + 2, 3);
        asm volatile("s_barrier" ::: "memory");
        asm volatile("s_waitcnt lgkmcnt(0)" ::: "memory");
        __builtin_amdgcn_sched_barrier(0);
        __builtin_amdgcn_s_setprio(1);
        MM(a1, b0, 4, 0)
        __builtin_amdgcn_s_setprio(0);
        if (tt + 2 < NT) {
            asm volatile("s_waitcnt vmcnt(4)" ::: "memory");
        } else {
            asm volatile("s_waitcnt vmcnt(0)" ::: "memory");
        }
        asm volatile("s_barrier" ::: "memory");
    }

    // epilogue: D col = lane&15 (n), row = (lane>>4)*4 + reg (m)
    const int bb = m0 >> 12;
    const int ms = (m0 & 4095) + wm * 128 + kq * 4;
    #pragma unroll
    for (int j = 0; j < 4; ++j) {
        const int n = n0 + wn * 64 + j * 16 + lr;
        const float bv = bias[n];
        float* ob = out + (size_t)bb * 4194304 + (size_t)n * 4096 + ms;
        #pragma unroll
        for (int i = 0; i < 8; ++i) {
            f32x4 v = acc[i][j];
            float4 o = make_float4(fmaxf(v[0] + bv, 0.f), fmaxf(v[1] + bv, 0.f),
                                   fmaxf(v[2] + bv, 0.f), fmaxf(v[3] + bv, 0.f));
            *(float4*)(ob + i * 16) = o;
        }
    }
    #undef LDA
    #undef LDB
    #undef MM
    #undef PH_OPEN
    #undef PH_CLOSE
}

// ---------- launch ----------
extern "C" void kernel_launch(void* const* d_in, const int* in_sizes, int n_in,
                              void* d_out, int out_size, void* d_ws, size_t ws_size,
                              hipStream_t stream)
{
    const float* x    = (const float*)d_in[0];
    const float* W    = (const float*)d_in[1];
    const float* bias = (const float*)d_in[2];
    float* out        = (float*)d_out;

    char* ws = (char*)d_ws;
    // xT: 32768*1088*2 = 71,303,168 B ; Wb: 1088*1024*2 = 2,228,224 B ; fpart: 8*25*32768*4 = 26,214,400 B
    unsigned short* xT = (unsigned short*)ws;
    unsigned short* Wb = (unsigned short*)(ws + 71303168);
    float* fpart       = (float*)(ws + 73531392);

    kWb_conv<<<1024, 256, 0, stream>>>(W, Wb);
    kT_conv <<<4096, 256, 0, stream>>>(x, xT);
    k1a_corr<<<256,  256, 0, stream>>>(x, fpart);
    k1b_norm<<<128,  256, 0, stream>>>(fpart, xT);
    kgemm   <<<512,  512, 0, stream>>>(xT, Wb, bias, out);
}

// Round 3
// 234.792 us; speedup vs baseline: 1.1765x; 1.1647x over previous
//
#include <hip/hip_runtime.h>

// ---------- types ----------
typedef __attribute__((ext_vector_type(8))) short bf16x8;   // 8 bf16 (4 VGPRs)
typedef __attribute__((ext_vector_type(4))) float f32x4;

__device__ __forceinline__ unsigned short f2bf(float f) {
    unsigned int u = __float_as_uint(f);
    unsigned int r = (u + 0x7fffu + ((u >> 16) & 1u)) >> 16;   // RNE
    return (unsigned short)r;
}

// Problem constants
// x: (8,1024,64,64) f32; W: (1024,1049) f32; b: (1024,)
// out: (8,1024,64,64) f32
// M = 32768, K = 1049 -> pad 1088 (17 K-tiles of 64), N = 1024
#define KPAD 1088
#define NT   17

// ---------- kernel: W (1024,1049) f32 -> Wb[n][k] bf16, k padded to 1088 ----------
__global__ void kWb_conv(const float* __restrict__ W, unsigned short* __restrict__ Wb)
{
    const int o = blockIdx.x;
    for (int k = threadIdx.x; k < KPAD; k += 256) {
        float v = (k < 1049) ? W[(size_t)o * 1049 + k] : 0.f;
        Wb[(size_t)o * KPAD + k] = f2bf(v);
    }
}

// ---------- kernel: transpose+convert x -> xT[m][k] bf16 (k<1024 region) ----------
// block: 64 m x 128 c. Register 4x4 transpose -> LDS (chunk-XOR swizzle) -> coalesced writes.
__global__ __launch_bounds__(256) void kT_conv(const float* __restrict__ x,
                                               unsigned short* __restrict__ xT)
{
    __shared__ unsigned short tile[64][128];   // 16KB; 16 chunks of 16B per row, XOR-swizzled
    const int bid = blockIdx.x;          // 4096 = 512 mtiles * 8 ctiles
    const int mst = bid >> 3;
    const int ct  = bid & 7;
    const int m0  = mst * 64;
    const int b   = m0 >> 12, ms0 = m0 & 4095;
    const int t   = threadIdx.x;
    const int msq = (t & 15) * 4;        // m offset 0..60
    const int cg  = t >> 4;              // 0..15 channel-group (8 ch)
    const int c0  = ct * 128 + cg * 8;

    const float* src = x + ((size_t)b * 1024 + c0) * 4096 + ms0 + msq;
    float4 v[8];
    #pragma unroll
    for (int j = 0; j < 8; ++j)
        v[j] = *(const float4*)(src + (size_t)j * 4096);

    #pragma unroll
    for (int p = 0; p < 4; ++p) {
        unsigned int w[4];
        #pragma unroll
        for (int q = 0; q < 4; ++q) {
            float lo = ((const float*)&v[2 * q])[p];
            float hi = ((const float*)&v[2 * q + 1])[p];
            w[q] = (unsigned int)f2bf(lo) | ((unsigned int)f2bf(hi) << 16);
        }
        const int row = msq + p;
        const int pch = cg ^ ((row >> 2) & 15);      // swizzle (involution)
        *(uint4*)&tile[row][pch * 8] = make_uint4(w[0], w[1], w[2], w[3]);
    }
    __syncthreads();

    #pragma unroll
    for (int q = 0; q < 4; ++q) {
        const int flat = q * 256 + t;                // 0..1023
        const int row  = flat >> 4, ch = flat & 15;
        const int pch  = ch ^ ((row >> 2) & 15);
        uint4 val = *(const uint4*)&tile[row][pch * 8];
        *(uint4*)((char*)xT + (size_t)(m0 + row) * (KPAD * 2) + (size_t)(ct * 128 + ch * 8) * 2) = val;
    }
}

// ---------- kernel: local self-correlation partials ----------
// grid 512 = split(16) * b(8) * rowgroup(4: 16 rows). 256 thr: 16 rows x 16 col-strips(P=4)
// 64 channels per block, f32 LDS slab [20 rows][68 cols], slab col = image col + 2.
// __launch_bounds__(256, 2): acc[25][4] (100 f32) MUST stay in VGPRs — the default
// budget (64-68 VGPR) spills it and was the round-2 2x regression.
__global__ __launch_bounds__(256, 2) void k1a_corr(const float* __restrict__ x,
                                                   float* __restrict__ fpart)
{
    __shared__ float slab[2][20][68];
    const int bid   = blockIdx.x;
    const int split = bid & 15;
    const int b     = (bid >> 4) & 7;
    const int rg    = bid >> 7;
    const int y0    = rg * 16;
    const int t     = threadIdx.x;
    const int tc    = t & 15, tr = t >> 4;
    const int cs    = tc * 4;

    if (t < 160) {
        int buf = t / 80, rem = t % 80;
        int r = rem >> 2, cc = rem & 3;
        slab[buf][r][(cc < 2) ? cc : (64 + cc)] = 0.f;
    }

    float acc[25][4];
    #pragma unroll
    for (int s = 0; s < 25; ++s)
        #pragma unroll
        for (int p = 0; p < 4; ++p) acc[s][p] = 0.f;

    const float* xb = x + ((size_t)b * 1024 + split * 64) * 4096;

    auto stage = [&](int i, int buf) {
        const float* src = xb + (size_t)i * 4096;
        #pragma unroll
        for (int pass = 0; pass < 2; ++pass) {
            int idx = t + pass * 256;
            if (idx < 320) {
                int r = idx >> 4, c4 = idx & 15;
                int y = y0 - 2 + r;
                float4 v = make_float4(0.f, 0.f, 0.f, 0.f);
                if (y >= 0 && y < 64) v = *(const float4*)(src + y * 64 + c4 * 4);
                float2* dst = (float2*)&slab[buf][r][2 + c4 * 4];
                dst[0] = make_float2(v.x, v.y);
                dst[1] = make_float2(v.z, v.w);
            }
        }
    };

    stage(0, 0);
    for (int i = 0; i < 64; ++i) {
        __syncthreads();
        if (i + 1 < 64) stage(i + 1, (i + 1) & 1);
        const int buf = i & 1;
        const float* base = &slab[buf][tr][cs];

        float ctr[4], wf[8];
        {
            const float4* pr = (const float4*)(base + 2 * 68);
            float4 a = pr[0], b4 = pr[1];
            wf[0]=a.x; wf[1]=a.y; wf[2]=a.z; wf[3]=a.w;
            wf[4]=b4.x; wf[5]=b4.y; wf[6]=b4.z; wf[7]=b4.w;
            ctr[0]=wf[2]; ctr[1]=wf[3]; ctr[2]=wf[4]; ctr[3]=wf[5];
            #pragma unroll
            for (int dx = -2; dx <= 2; ++dx)
                #pragma unroll
                for (int p = 0; p < 4; ++p)
                    acc[10 + dx + 2][p] += wf[p + 2 + dx] * ctr[p];
        }
        #pragma unroll
        for (int r = 0; r < 5; ++r) {
            if (r == 2) continue;
            const float4* pr = (const float4*)(base + r * 68);
            float4 a = pr[0], b4 = pr[1];
            wf[0]=a.x; wf[1]=a.y; wf[2]=a.z; wf[3]=a.w;
            wf[4]=b4.x; wf[5]=b4.y; wf[6]=b4.z; wf[7]=b4.w;
            #pragma unroll
            for (int dx = -2; dx <= 2; ++dx)
                #pragma unroll
                for (int p = 0; p < 4; ++p)
                    acc[r * 5 + dx + 2][p] += wf[p + 2 + dx] * ctr[p];
        }
    }

    const int mbase = b * 4096 + (y0 + tr) * 64 + cs;
    #pragma unroll
    for (int s = 0; s < 25; ++s) {
        *(float4*)(fpart + (size_t)(split * 25 + s) * 32768 + mbase) =
            make_float4(acc[s][0], acc[s][1], acc[s][2], acc[s][3]);
    }
}

// ---------- kernel: reduce 16 partials, L2-normalize, write bf16 into xT[m][1024..1088) ----------
__global__ void k1b_norm(const float* __restrict__ fpart, unsigned short* __restrict__ xT)
{
    const int m = blockIdx.x * 256 + threadIdx.x;
    float f[25];
    #pragma unroll
    for (int s = 0; s < 25; ++s) {
        float v = 0.f;
        #pragma unroll
        for (int sp = 0; sp < 16; ++sp)
            v += fpart[(size_t)(sp * 25 + s) * 32768 + m];
        f[s] = v;
    }
    float ss = 1e-6f;
    #pragma unroll
    for (int s = 0; s < 25; ++s) ss += f[s] * f[s];
    const float inv = 1.f / sqrtf(ss);

    unsigned int w[16];
    #pragma unroll
    for (int q = 0; q < 16; ++q) w[q] = 0u;
    #pragma unroll
    for (int s = 0; s < 25; ++s) {
        unsigned int h = f2bf(f[s] * inv);
        w[s >> 1] |= h << ((s & 1) * 16);
    }
    uint4* dst = (uint4*)((char*)xT + (size_t)m * (KPAD * 2) + 2048);
    dst[0] = make_uint4(w[0],  w[1],  w[2],  w[3]);
    dst[1] = make_uint4(w[4],  w[5],  w[6],  w[7]);
    dst[2] = make_uint4(w[8],  w[9],  w[10], w[11]);
    dst[3] = make_uint4(w[12], w[13], w[14], w[15]);
    uint4 z = make_uint4(0u, 0u, 0u, 0u);
    dst[4] = z; dst[5] = z; dst[6] = z; dst[7] = z;   // pad 1056..1088 = 0
}

// ---------- kernel: 256x256 8-phase GEMM, out = relu(xT @ Wb^T + bias) ----------
// BM=BN=256, BK=64, 8 waves (2M x 4N), per-wave 128x64, 16x16x32 bf16 MFMA.
// LDS 128KB: A/B double-buffered [2][256][64] bf16 with 8-slot XOR swizzle.
// Counted vmcnt(4) pipeline: stage {ph1:Alo(t+1), ph2:Ahi(t+1), ph3:Blo(t+2), ph4:Bhi(t+2)}.
__global__ __launch_bounds__(512, 2) void kgemm(const unsigned short* __restrict__ xT,
                                                const unsigned short* __restrict__ Wb,
                                                const float* __restrict__ bias,
                                                float* __restrict__ out)
{
    __shared__ unsigned short LA[2][256][64];   // 64KB
    __shared__ unsigned short LB[2][256][64];   // 64KB

    const int bid = blockIdx.x;                 // 512 blocks
    const int wg  = (bid & 7) * 64 + (bid >> 3);// XCD chunk swizzle (512 % 8 == 0, bijective)
    const int mt  = wg >> 2, nt = wg & 3;
    const int m0  = mt * 256, n0 = nt * 256;
    const int t   = threadIdx.x;
    const int l   = t & 63, w = t >> 6;
    const int lr  = l & 15, kq = l >> 4;
    const int wm  = w >> 2, wn = w & 3;

    // staging geometry: lane writes phys 16B chunk (row = w*8 + (l>>3), slot = l&7);
    // source fetches logical slot (l&7) ^ (l>>3)  -> read-side XOR undoes it.
    const int sr = l >> 3;
    const int sp = (l & 7) ^ sr;
    const unsigned short* gA = xT + (size_t)(m0 + w * 8 + sr) * KPAD + sp * 8;
    const unsigned short* gB = Wb + (size_t)(n0 + w * 8 + sr) * KPAD + sp * 8;

    // half: 0 = A rows[0:128), 1 = A[128:256), 2 = B[0:128), 3 = B[128:256)
    auto STAGE = [&](int tt, int half) {
        if ((unsigned)tt >= NT) return;
        const int db = tt & 1;
        const size_t ko = (size_t)tt * 64;
        if (half < 2) {
            const unsigned short* g = gA + (size_t)(half * 128) * KPAD + ko;
            __builtin_amdgcn_global_load_lds((const void*)g,
                (void*)&LA[db][half * 128 + w * 8][0], 16, 0, 0);
            __builtin_amdgcn_global_load_lds((const void*)(g + (size_t)64 * KPAD),
                (void*)&LA[db][half * 128 + 64 + w * 8][0], 16, 0, 0);
        } else {
            const int hb = half - 2;
            const unsigned short* g = gB + (size_t)(hb * 128) * KPAD + ko;
            __builtin_amdgcn_global_load_lds((const void*)g,
                (void*)&LB[db][hb * 128 + w * 8][0], 16, 0, 0);
            __builtin_amdgcn_global_load_lds((const void*)(g + (size_t)64 * KPAD),
                (void*)&LB[db][hb * 128 + 64 + w * 8][0], 16, 0, 0);
        }
    };

    f32x4 zero = {0.f, 0.f, 0.f, 0.f};
    f32x4 acc[8][4];
    #pragma unroll
    for (int i = 0; i < 8; ++i)
        #pragma unroll
        for (int j = 0; j < 4; ++j) acc[i][j] = zero;

    bf16x8 a0[4][2], a1[4][2], b0[2][2], b1[2][2];

    #define LDA(dst, db, ih)                                                     \
        _Pragma("unroll")                                                        \
        for (int i = 0; i < 4; ++i) {                                            \
            _Pragma("unroll")                                                    \
            for (int ks = 0; ks < 2; ++ks) {                                     \
                const int row = wm * 128 + ((ih) * 4 + i) * 16 + lr;             \
                const int slot = (ks * 4 + kq) ^ (row & 7);                      \
                dst[i][ks] = *(const bf16x8*)&LA[db][row][slot * 8];             \
            }                                                                    \
        }
    #define LDB(dst, db, jh)                                                     \
        _Pragma("unroll")                                                        \
        for (int j = 0; j < 2; ++j) {                                            \
            _Pragma("unroll")                                                    \
            for (int ks = 0; ks < 2; ++ks) {                                     \
                const int row = wn * 64 + ((jh) * 2 + j) * 16 + lr;              \
                const int slot = (ks * 4 + kq) ^ (row & 7);                      \
                dst[j][ks] = *(const bf16x8*)&LB[db][row][slot * 8];             \
            }                                                                    \
        }
    #define MM(A, B, i0, j0)                                                     \
        _Pragma("unroll")                                                        \
        for (int ks = 0; ks < 2; ++ks) {                                         \
            _Pragma("unroll")                                                    \
            for (int i = 0; i < 4; ++i) {                                        \
                _Pragma("unroll")                                                \
                for (int j = 0; j < 2; ++j)                                      \
                    acc[(i0) + i][(j0) + j] = __builtin_amdgcn_mfma_f32_16x16x32_bf16( \
                        A[i][ks], B[j][ks], acc[(i0) + i][(j0) + j], 0, 0, 0);   \
            }                                                                    \
        }
    #define PH_OPEN()                                                            \
        asm volatile("s_barrier" ::: "memory");                                  \
        asm volatile("s_waitcnt lgkmcnt(0)" ::: "memory");                       \
        __builtin_amdgcn_sched_barrier(0);                                       \
        __builtin_amdgcn_s_setprio(1);
    #define PH_CLOSE()                                                           \
        __builtin_amdgcn_s_setprio(0);                                           \
        asm volatile("s_barrier" ::: "memory");

    // prologue: tile 0 complete + B halves of tile 1 in flight
    STAGE(0, 0); STAGE(0, 1); STAGE(0, 2); STAGE(0, 3);
    STAGE(1, 2); STAGE(1, 3);
    asm volatile("s_waitcnt vmcnt(4)" ::: "memory");
    asm volatile("s_barrier" ::: "memory");

    for (int tt = 0; tt < NT; ++tt) {
        const int db = tt & 1;
        // ---- phase 1: read A-frags 0..3 + B-frags 0..1; stage A-lo(t+1); MFMA q(0,0)
        LDA(a0, db, 0)
        LDB(b0, db, 0)
        STAGE(tt + 1, 0);
        PH_OPEN()
        MM(a0, b0, 0, 0)
        PH_CLOSE()
        // ---- phase 2: read B-frags 2..3; stage A-hi(t+1); MFMA q(0,1)
        LDB(b1, db, 1)
        STAGE(tt + 1, 1);
        PH_OPEN()
        MM(a0, b1, 0, 2)
        PH_CLOSE()
        // ---- phase 3: read A-frags 4..7; stage B-lo(t+2); MFMA q(1,1)
        LDA(a1, db, 1)
        STAGE(tt + 2, 2);
        PH_OPEN()
        MM(a1, b1, 4, 2)
        PH_CLOSE()
        // ---- phase 4: stage B-hi(t+2); MFMA q(1,0); boundary vmcnt
        STAGE(tt + 2, 3);
        asm volatile("s_barrier" ::: "memory");
        asm volatile("s_waitcnt lgkmcnt(0)" ::: "memory");
        __builtin_amdgcn_sched_barrier(0);
        __builtin_amdgcn_s_setprio(1);
        MM(a1, b0, 4, 0)
        __builtin_amdgcn_s_setprio(0);
        if (tt + 2 < NT) {
            asm volatile("s_waitcnt vmcnt(4)" ::: "memory");
        } else {
            asm volatile("s_waitcnt vmcnt(0)" ::: "memory");
        }
        asm volatile("s_barrier" ::: "memory");
    }

    // epilogue: D col = lane&15 (n), row = (lane>>4)*4 + reg (m)
    const int bb = m0 >> 12;
    const int ms = (m0 & 4095) + wm * 128 + kq * 4;
    #pragma unroll
    for (int j = 0; j < 4; ++j) {
        const int n = n0 + wn * 64 + j * 16 + lr;
        const float bv = bias[n];
        float* ob = out + (size_t)bb * 4194304 + (size_t)n * 4096 + ms;
        #pragma unroll
        for (int i = 0; i < 8; ++i) {
            f32x4 v = acc[i][j];
            float4 o = make_float4(fmaxf(v[0] + bv, 0.f), fmaxf(v[1] + bv, 0.f),
                                   fmaxf(v[2] + bv, 0.f), fmaxf(v[3] + bv, 0.f));
            *(float4*)(ob + i * 16) = o;
        }
    }
    #undef LDA
    #undef LDB
    #undef MM
    #undef PH_OPEN
    #undef PH_CLOSE
}

// ---------- launch ----------
extern "C" void kernel_launch(void* const* d_in, const int* in_sizes, int n_in,
                              void* d_out, int out_size, void* d_ws, size_t ws_size,
                              hipStream_t stream)
{
    const float* x    = (const float*)d_in[0];
    const float* W    = (const float*)d_in[1];
    const float* bias = (const float*)d_in[2];
    float* out        = (float*)d_out;

    char* ws = (char*)d_ws;
    // ws: xT 32768*1088*2 = 71,303,168 B ; Wb: 1088*1024*2 = 2,228,224 B  (total 73.5MB)
    // fpart (16*25*32768*4 = 52.4MB) lives in d_out scratch (134MB); kgemm overwrites
    // all of d_out afterwards, so timing replays stay deterministic.
    unsigned short* xT = (unsigned short*)ws;
    unsigned short* Wb = (unsigned short*)(ws + 71303168);
    float* fpart       = (float*)d_out;

    kWb_conv<<<1024, 256, 0, stream>>>(W, Wb);
    kT_conv <<<4096, 256, 0, stream>>>(x, xT);
    k1a_corr<<<512,  256, 0, stream>>>(x, fpart);
    k1b_norm<<<128,  256, 0, stream>>>(fpart, xT);
    kgemm   <<<512,  512, 0, stream>>>(xT, Wb, bias, out);
}

// Round 4
// 220.594 us; speedup vs baseline: 1.2522x; 1.0644x over previous
//
#include <hip/hip_runtime.h>

// ---------- types ----------
typedef __attribute__((ext_vector_type(8))) short bf16x8;   // 8 bf16 (4 VGPRs)
typedef __attribute__((ext_vector_type(4))) float f32x4;

__device__ __forceinline__ unsigned short f2bf(float f) {
    unsigned int u = __float_as_uint(f);
    unsigned int r = (u + 0x7fffu + ((u >> 16) & 1u)) >> 16;   // RNE
    return (unsigned short)r;
}

// x: (8,1024,64,64) f32; W: (1024,1049) f32; b: (1024,); out: (8,1024,64,64) f32
// M = 32768, K = 1049 -> pad 1088 (17 K-tiles of 64), N = 1024
#define KPAD 1088
#define NT   17

// ---------- kernel: W (1024,1049) f32 -> Wb[n][k] bf16, k padded to 1088 ----------
__global__ void kWb_conv(const float* __restrict__ W, unsigned short* __restrict__ Wb)
{
    const int o = blockIdx.x;
    for (int k = threadIdx.x; k < KPAD; k += 256) {
        float v = (k < 1049) ? W[(size_t)o * 1049 + k] : 0.f;
        Wb[(size_t)o * KPAD + k] = f2bf(v);
    }
}

// ---------- kernel: transpose+convert x -> xT[m][k] bf16 (k<1024 region) ----------
__global__ __launch_bounds__(256) void kT_conv(const float* __restrict__ x,
                                               unsigned short* __restrict__ xT)
{
    __shared__ unsigned short tile[64][128];
    const int bid = blockIdx.x;          // 4096 = 512 mtiles * 8 ctiles
    const int mst = bid >> 3;
    const int ct  = bid & 7;
    const int m0  = mst * 64;
    const int b   = m0 >> 12, ms0 = m0 & 4095;
    const int t   = threadIdx.x;
    const int msq = (t & 15) * 4;
    const int cg  = t >> 4;
    const int c0  = ct * 128 + cg * 8;

    const float* src = x + ((size_t)b * 1024 + c0) * 4096 + ms0 + msq;
    float4 v[8];
    #pragma unroll
    for (int j = 0; j < 8; ++j)
        v[j] = *(const float4*)(src + (size_t)j * 4096);

    #pragma unroll
    for (int p = 0; p < 4; ++p) {
        unsigned int w[4];
        #pragma unroll
        for (int q = 0; q < 4; ++q) {
            float lo = ((const float*)&v[2 * q])[p];
            float hi = ((const float*)&v[2 * q + 1])[p];
            w[q] = (unsigned int)f2bf(lo) | ((unsigned int)f2bf(hi) << 16);
        }
        const int row = msq + p;
        const int pch = cg ^ ((row >> 2) & 15);
        *(uint4*)&tile[row][pch * 8] = make_uint4(w[0], w[1], w[2], w[3]);
    }
    __syncthreads();

    #pragma unroll
    for (int q = 0; q < 4; ++q) {
        const int flat = q * 256 + t;
        const int row  = flat >> 4, ch = flat & 15;
        const int pch  = ch ^ ((row >> 2) & 15);
        uint4 val = *(const uint4*)&tile[row][pch * 8];
        *(uint4*)((char*)xT + (size_t)(m0 + row) * (KPAD * 2) + (size_t)(ct * 128 + ch * 8) * 2) = val;
    }
}

// ---------- kernel: local self-correlation partials ----------
// grid 512 = split(16) * b(8) * rowgroup(4). 256 thr: 16 rows x 16 col-strips(P=4).
// T14 async-stage: global loads 2 channels ahead into regs; ds_write right after the
// barrier; compute covers the load latency (the __syncthreads vmcnt(0) drain then
// waits for loads issued a full compute-phase earlier — round-3's version stalled
// every iteration on just-issued loads).
__global__ __launch_bounds__(256, 2) void k1a_corr(const float* __restrict__ x,
                                                   float* __restrict__ fpart)
{
    __shared__ float slab[2][20][68];
    const int bid   = blockIdx.x;
    const int split = bid & 15;
    const int b     = (bid >> 4) & 7;
    const int rg    = bid >> 7;
    const int y0    = rg * 16;
    const int t     = threadIdx.x;
    const int tc    = t & 15, tr = t >> 4;
    const int cs    = tc * 4;

    if (t < 160) {
        int buf = t / 80, rem = t % 80;
        int r = rem >> 2, cc = rem & 3;
        slab[buf][r][(cc < 2) ? cc : (64 + cc)] = 0.f;
    }

    float acc[25][4];
    #pragma unroll
    for (int s = 0; s < 25; ++s)
        #pragma unroll
        for (int p = 0; p < 4; ++p) acc[s][p] = 0.f;

    const float* xb = x + ((size_t)b * 1024 + split * 64) * 4096;

    // per-thread staging geometry: item t (always) + item t+256 (t<64)
    const int r0 = t >> 4,         c40 = t & 15;
    const int y0r0 = y0 - 2 + r0;
    const int r1 = (t + 256) >> 4, c41 = t & 15;          // t<64 only
    const int y0r1 = y0 - 2 + r1;
    const bool has1 = (t < 64);

    #define K1A_LOAD(ch, VA, VB)                                                \
        {                                                                        \
            const float* s_ = xb + (size_t)(ch) * 4096;                          \
            VA = (y0r0 >= 0 && y0r0 < 64) ? *(const float4*)(s_ + y0r0 * 64 + c40 * 4) \
                                          : make_float4(0.f, 0.f, 0.f, 0.f);     \
            if (has1)                                                            \
                VB = (y0r1 >= 0 && y0r1 < 64) ? *(const float4*)(s_ + y0r1 * 64 + c41 * 4) \
                                              : make_float4(0.f, 0.f, 0.f, 0.f); \
        }
    #define K1A_WRITE(buf, VA, VB)                                               \
        {                                                                        \
            float2* d0 = (float2*)&slab[buf][r0][2 + c40 * 4];                   \
            d0[0] = make_float2(VA.x, VA.y);                                     \
            d0[1] = make_float2(VA.z, VA.w);                                     \
            if (has1) {                                                          \
                float2* d1 = (float2*)&slab[buf][r1][2 + c41 * 4];               \
                d1[0] = make_float2(VB.x, VB.y);                                 \
                d1[1] = make_float2(VB.z, VB.w);                                 \
            }                                                                    \
        }
    #define K1A_COMPUTE(buf)                                                     \
        {                                                                        \
            const float* base = &slab[buf][tr][cs];                              \
            float ctr[4], wf[8];                                                 \
            {                                                                    \
                const float4* pr = (const float4*)(base + 2 * 68);               \
                float4 a = pr[0], b4 = pr[1];                                    \
                wf[0]=a.x; wf[1]=a.y; wf[2]=a.z; wf[3]=a.w;                      \
                wf[4]=b4.x; wf[5]=b4.y; wf[6]=b4.z; wf[7]=b4.w;                  \
                ctr[0]=wf[2]; ctr[1]=wf[3]; ctr[2]=wf[4]; ctr[3]=wf[5];          \
                _Pragma("unroll")                                                \
                for (int dx = -2; dx <= 2; ++dx)                                 \
                    _Pragma("unroll")                                            \
                    for (int p = 0; p < 4; ++p)                                  \
                        acc[10 + dx + 2][p] += wf[p + 2 + dx] * ctr[p];          \
            }                                                                    \
            _Pragma("unroll")                                                    \
            for (int r = 0; r < 5; ++r) {                                        \
                if (r == 2) continue;                                            \
                const float4* pr = (const float4*)(base + r * 68);               \
                float4 a = pr[0], b4 = pr[1];                                    \
                wf[0]=a.x; wf[1]=a.y; wf[2]=a.z; wf[3]=a.w;                      \
                wf[4]=b4.x; wf[5]=b4.y; wf[6]=b4.z; wf[7]=b4.w;                  \
                _Pragma("unroll")                                                \
                for (int dx = -2; dx <= 2; ++dx)                                 \
                    _Pragma("unroll")                                            \
                    for (int p = 0; p < 4; ++p)                                  \
                        acc[r * 5 + dx + 2][p] += wf[p + 2 + dx] * ctr[p];       \
            }                                                                    \
        }

    float4 Sa0, Sa1, Sb0, Sb1;
    K1A_LOAD(0, Sa0, Sa1)                 // ch0
    K1A_LOAD(1, Sb0, Sb1)                 // ch1
    K1A_WRITE(0, Sa0, Sa1)                // stage ch0 -> buf0 (vmcnt wait auto)
    K1A_LOAD(2, Sa0, Sa1)                 // ch2 in flight
    __syncthreads();

    for (int i = 0; i < 64; i += 2) {
        // buf0 = ch i; Sb = ch i+1 (ready); Sa = ch i+2 (in flight)
        K1A_WRITE(1, Sb0, Sb1)            // stage ch i+1 -> buf1
        K1A_LOAD(min(i + 3, 63), Sb0, Sb1)
        K1A_COMPUTE(0)
        __syncthreads();
        // buf1 = ch i+1; Sa = ch i+2 (drained by sync); Sb = ch i+3 in flight
        K1A_WRITE(0, Sa0, Sa1)            // stage ch i+2 -> buf0
        K1A_LOAD(min(i + 4, 63), Sa0, Sa1)
        K1A_COMPUTE(1)
        __syncthreads();
    }
    #undef K1A_LOAD
    #undef K1A_WRITE
    #undef K1A_COMPUTE

    const int mbase = b * 4096 + (y0 + tr) * 64 + cs;
    #pragma unroll
    for (int s = 0; s < 25; ++s) {
        *(float4*)(fpart + (size_t)(split * 25 + s) * 32768 + mbase) =
            make_float4(acc[s][0], acc[s][1], acc[s][2], acc[s][3]);
    }
}

// ---------- kernel: reduce 16 partials, L2-normalize, write bf16 into xT[m][1024..1088) ----------
__global__ void k1b_norm(const float* __restrict__ fpart, unsigned short* __restrict__ xT)
{
    const int m = blockIdx.x * 256 + threadIdx.x;
    float f[25];
    #pragma unroll
    for (int s = 0; s < 25; ++s) {
        float v = 0.f;
        #pragma unroll
        for (int sp = 0; sp < 16; ++sp)
            v += fpart[(size_t)(sp * 25 + s) * 32768 + m];
        f[s] = v;
    }
    float ss = 1e-6f;
    #pragma unroll
    for (int s = 0; s < 25; ++s) ss += f[s] * f[s];
    const float inv = 1.f / sqrtf(ss);

    unsigned int w[16];
    #pragma unroll
    for (int q = 0; q < 16; ++q) w[q] = 0u;
    #pragma unroll
    for (int s = 0; s < 25; ++s) {
        unsigned int h = f2bf(f[s] * inv);
        w[s >> 1] |= h << ((s & 1) * 16);
    }
    uint4* dst = (uint4*)((char*)xT + (size_t)m * (KPAD * 2) + 2048);
    dst[0] = make_uint4(w[0],  w[1],  w[2],  w[3]);
    dst[1] = make_uint4(w[4],  w[5],  w[6],  w[7]);
    dst[2] = make_uint4(w[8],  w[9],  w[10], w[11]);
    dst[3] = make_uint4(w[12], w[13], w[14], w[15]);
    uint4 z = make_uint4(0u, 0u, 0u, 0u);
    dst[4] = z; dst[5] = z; dst[6] = z; dst[7] = z;
}

// ---------- kernel: 256x256 8-phase GEMM, frag-reads pipelined one phase ahead ----------
// BM=BN=256, BK=64, 8 waves (2M x 4N), per-wave 128x64, 16x16x32 bf16 MFMA.
// LDS 128KB: A/B double-buffered [2][256][64] with 8-slot XOR swizzle (conflicts = 0).
// Schedule per tile t (db = t&1); invariant entering t: B(t+1)x4 loads outstanding.
//   ph1: STAGE A(t+1) lo+hi | bar, lgkm(4)  | MM(a0,b0)
//   ph2: read a1            | bar, lgkm(8)  | MM(a0,b1)     (STAGE B(t+2) lo)
//   ph3: STAGE B(t+2) hi, vmcnt(4) [drains B(t+1)+A(t+1)] | bar, lgkm(0) | MM(a1,b1); read a0'
//   ph4: (merged barrier)     lgkm(8)       | MM(a1,b0); read b0',b1'
// Every MM's operands were ds_read >= 1 phase earlier -> lgkm waits are cheap and the
// LDS pipe overlaps the MFMA pipe (round-3 serialized them: MfmaUtil 28.6%).
__global__ __launch_bounds__(512, 2) void kgemm(const unsigned short* __restrict__ xT,
                                                const unsigned short* __restrict__ Wb,
                                                const float* __restrict__ bias,
                                                float* __restrict__ out)
{
    __shared__ unsigned short LA[2][256][64];   // 64KB
    __shared__ unsigned short LB[2][256][64];   // 64KB

    const int bid = blockIdx.x;                 // 512 blocks
    const int wg  = (bid & 7) * 64 + (bid >> 3);
    const int mt  = wg >> 2, nt = wg & 3;
    const int m0  = mt * 256, n0 = nt * 256;
    const int t   = threadIdx.x;
    const int l   = t & 63, w = t >> 6;
    const int lr  = l & 15, kq = l >> 4;
    const int wm  = w >> 2, wn = w & 3;

    const int sr = l >> 3;
    const int sp = (l & 7) ^ sr;
    const unsigned short* gA = xT + (size_t)(m0 + w * 8 + sr) * KPAD + sp * 8;
    const unsigned short* gB = Wb + (size_t)(n0 + w * 8 + sr) * KPAD + sp * 8;

    auto STAGE = [&](int tt, int half) {
        if ((unsigned)tt >= NT) return;
        const int db = tt & 1;
        const size_t ko = (size_t)tt * 64;
        if (half < 2) {
            const unsigned short* g = gA + (size_t)(half * 128) * KPAD + ko;
            __builtin_amdgcn_global_load_lds((const void*)g,
                (void*)&LA[db][half * 128 + w * 8][0], 16, 0, 0);
            __builtin_amdgcn_global_load_lds((const void*)(g + (size_t)64 * KPAD),
                (void*)&LA[db][half * 128 + 64 + w * 8][0], 16, 0, 0);
        } else {
            const int hb = half - 2;
            const unsigned short* g = gB + (size_t)(hb * 128) * KPAD + ko;
            __builtin_amdgcn_global_load_lds((const void*)g,
                (void*)&LB[db][hb * 128 + w * 8][0], 16, 0, 0);
            __builtin_amdgcn_global_load_lds((const void*)(g + (size_t)64 * KPAD),
                (void*)&LB[db][hb * 128 + 64 + w * 8][0], 16, 0, 0);
        }
    };

    f32x4 zero = {0.f, 0.f, 0.f, 0.f};
    f32x4 acc[8][4];
    #pragma unroll
    for (int i = 0; i < 8; ++i)
        #pragma unroll
        for (int j = 0; j < 4; ++j) acc[i][j] = zero;

    bf16x8 a0[4][2], a1[4][2], b0[2][2], b1[2][2];

    #define LDA(dst, dbuf, ih)                                                   \
        _Pragma("unroll")                                                        \
        for (int i = 0; i < 4; ++i) {                                            \
            _Pragma("unroll")                                                    \
            for (int ks = 0; ks < 2; ++ks) {                                     \
                const int row = wm * 128 + ((ih) * 4 + i) * 16 + lr;             \
                const int slot = (ks * 4 + kq) ^ (row & 7);                      \
                dst[i][ks] = *(const bf16x8*)&LA[dbuf][row][slot * 8];           \
            }                                                                    \
        }
    #define LDB(dst, dbuf, jh)                                                   \
        _Pragma("unroll")                                                        \
        for (int j = 0; j < 2; ++j) {                                            \
            _Pragma("unroll")                                                    \
            for (int ks = 0; ks < 2; ++ks) {                                     \
                const int row = wn * 64 + ((jh) * 2 + j) * 16 + lr;              \
                const int slot = (ks * 4 + kq) ^ (row & 7);                      \
                dst[j][ks] = *(const bf16x8*)&LB[dbuf][row][slot * 8];           \
            }                                                                    \
        }
    #define MM(A, B, i0, j0)                                                     \
        _Pragma("unroll")                                                        \
        for (int ks = 0; ks < 2; ++ks) {                                         \
            _Pragma("unroll")                                                    \
            for (int i = 0; i < 4; ++i) {                                        \
                _Pragma("unroll")                                                \
                for (int j = 0; j < 2; ++j)                                      \
                    acc[(i0) + i][(j0) + j] = __builtin_amdgcn_mfma_f32_16x16x32_bf16( \
                        A[i][ks], B[j][ks], acc[(i0) + i][(j0) + j], 0, 0, 0);   \
            }                                                                    \
        }
    #define BAR()  asm volatile("s_barrier" ::: "memory");
    #define LGKM(n) asm volatile("s_waitcnt lgkmcnt(" #n ")" ::: "memory");      \
                    __builtin_amdgcn_sched_barrier(0);

    // prologue: A(0),B(0),B(1) staged; drain A(0),B(0); preload frags of tile 0
    STAGE(0, 0); STAGE(0, 1); STAGE(0, 2); STAGE(0, 3);
    STAGE(1, 2); STAGE(1, 3);
    asm volatile("s_waitcnt vmcnt(4)" ::: "memory");
    BAR()
    LDA(a0, 0, 0)
    LDB(b0, 0, 0)
    LDB(b1, 0, 1)

    for (int tt = 0; tt < NT; ++tt) {
        const int db = tt & 1;
        // ---- ph1: stage A(t+1); MM(a0,b0)  [a0,b0 read >=1 phase ago]
        STAGE(tt + 1, 0);
        STAGE(tt + 1, 1);
        BAR()
        LGKM(4)                       // drain a0', b0' (oldest); b1' may remain
        __builtin_amdgcn_s_setprio(1);
        MM(a0, b0, 0, 0)
        __builtin_amdgcn_s_setprio(0);
        BAR()
        // ---- ph2: read a1(cur); stage B(t+2)-lo; MM(a0,b1)
        LDA(a1, db, 1)
        STAGE(tt + 2, 2);
        BAR()
        LGKM(8)                       // drain b1'; allow a1's 8 reads
        __builtin_amdgcn_s_setprio(1);
        MM(a0, b1, 0, 2)
        __builtin_amdgcn_s_setprio(0);
        BAR()
        // ---- ph3: stage B(t+2)-hi; vmcnt drains B(t+1)+A(t+1); MM(a1,b1); read a0(next)
        STAGE(tt + 2, 3);
        if (tt + 2 < NT) {
            asm volatile("s_waitcnt vmcnt(4)" ::: "memory");
        } else {
            asm volatile("s_waitcnt vmcnt(0)" ::: "memory");
        }
        BAR()
        LGKM(0)                       // a1 must be done (issued 1 phase ago)
        __builtin_amdgcn_s_setprio(1);
        MM(a1, b1, 4, 2)
        __builtin_amdgcn_sched_barrier(0);
        if (tt + 1 < NT) { LDA(a0, db ^ 1, 0) }     // next tile's a0 from other buffer
        __builtin_amdgcn_s_setprio(0);
        BAR()
        // ---- ph4 (merged open barrier): MM(a1,b0); read b0',b1'(next)
        LGKM(8)                       // allow a0' reads; a1/b0 already drained
        __builtin_amdgcn_s_setprio(1);
        MM(a1, b0, 4, 0)
        __builtin_amdgcn_sched_barrier(0);
        if (tt + 1 < NT) { LDB(b0, db ^ 1, 0) LDB(b1, db ^ 1, 1) }
        __builtin_amdgcn_s_setprio(0);
        BAR()
    }

    // epilogue: D col = lane&15 (n), row = (lane>>4)*4 + reg (m)
    const int bb = m0 >> 12;
    const int ms = (m0 & 4095) + wm * 128 + kq * 4;
    #pragma unroll
    for (int j = 0; j < 4; ++j) {
        const int n = n0 + wn * 64 + j * 16 + lr;
        const float bv = bias[n];
        float* ob = out + (size_t)bb * 4194304 + (size_t)n * 4096 + ms;
        #pragma unroll
        for (int i = 0; i < 8; ++i) {
            f32x4 v = acc[i][j];
            float4 o = make_float4(fmaxf(v[0] + bv, 0.f), fmaxf(v[1] + bv, 0.f),
                                   fmaxf(v[2] + bv, 0.f), fmaxf(v[3] + bv, 0.f));
            *(float4*)(ob + i * 16) = o;
        }
    }
    #undef LDA
    #undef LDB
    #undef MM
    #undef BAR
    #undef LGKM
}

// ---------- launch ----------
extern "C" void kernel_launch(void* const* d_in, const int* in_sizes, int n_in,
                              void* d_out, int out_size, void* d_ws, size_t ws_size,
                              hipStream_t stream)
{
    const float* x    = (const float*)d_in[0];
    const float* W    = (const float*)d_in[1];
    const float* bias = (const float*)d_in[2];
    float* out        = (float*)d_out;

    char* ws = (char*)d_ws;
    // ws: xT 32768*1088*2 = 71,303,168 B ; Wb 1088*1024*2 = 2,228,224 B (total 73.5MB)
    // fpart (16*25*32768*4 = 52.4MB) lives in d_out scratch; kgemm overwrites all of
    // d_out afterwards, so timing replays stay deterministic.
    unsigned short* xT = (unsigned short*)ws;
    unsigned short* Wb = (unsigned short*)(ws + 71303168);
    float* fpart       = (float*)d_out;

    kWb_conv<<<1024, 256, 0, stream>>>(W, Wb);
    kT_conv <<<4096, 256, 0, stream>>>(x, xT);
    k1a_corr<<<512,  256, 0, stream>>>(x, fpart);
    k1b_norm<<<128,  256, 0, stream>>>(fpart, xT);
    kgemm   <<<512,  512, 0, stream>>>(xT, Wb, bias, out);
}

// Round 6
// 211.727 us; speedup vs baseline: 1.3047x; 1.0419x over previous
//
#include <hip/hip_runtime.h>

// ---------- types ----------
typedef __attribute__((ext_vector_type(8))) short bf16x8;   // 8 bf16 (4 VGPRs)
typedef __attribute__((ext_vector_type(4))) float f32x4;

__device__ __forceinline__ unsigned short f2bf(float f) {
    unsigned int u = __float_as_uint(f);
    unsigned int r = (u + 0x7fffu + ((u >> 16) & 1u)) >> 16;   // RNE
    return (unsigned short)r;
}

// x: (8,1024,64,64) f32; W: (1024,1049) f32; b: (1024,); out: (8,1024,64,64) f32
// M = 32768, K = 1049 -> pad 1088 (17 K-tiles of 64), N = 1024
#define KPAD 1088
#define NT   17

// ---------- kernel: W (1024,1049) f32 -> Wb[n][k] bf16, k padded to 1088 ----------
__global__ void kWb_conv(const float* __restrict__ W, unsigned short* __restrict__ Wb)
{
    const int o = blockIdx.x;
    for (int k = threadIdx.x; k < KPAD; k += 256) {
        float v = (k < 1049) ? W[(size_t)o * 1049 + k] : 0.f;
        Wb[(size_t)o * KPAD + k] = f2bf(v);
    }
}

// ---------- kernel: transpose+convert x -> xT[m][k] bf16 (k<1024 region) ----------
__global__ __launch_bounds__(256) void kT_conv(const float* __restrict__ x,
                                               unsigned short* __restrict__ xT)
{
    __shared__ unsigned short tile[64][128];
    const int bid = blockIdx.x;          // 4096 = 512 mtiles * 8 ctiles
    const int mst = bid >> 3;
    const int ct  = bid & 7;
    const int m0  = mst * 64;
    const int b   = m0 >> 12, ms0 = m0 & 4095;
    const int t   = threadIdx.x;
    const int msq = (t & 15) * 4;
    const int cg  = t >> 4;
    const int c0  = ct * 128 + cg * 8;

    const float* src = x + ((size_t)b * 1024 + c0) * 4096 + ms0 + msq;
    float4 v[8];
    #pragma unroll
    for (int j = 0; j < 8; ++j)
        v[j] = *(const float4*)(src + (size_t)j * 4096);

    #pragma unroll
    for (int p = 0; p < 4; ++p) {
        unsigned int w[4];
        #pragma unroll
        for (int q = 0; q < 4; ++q) {
            float lo = ((const float*)&v[2 * q])[p];
            float hi = ((const float*)&v[2 * q + 1])[p];
            w[q] = (unsigned int)f2bf(lo) | ((unsigned int)f2bf(hi) << 16);
        }
        const int row = msq + p;
        const int pch = cg ^ ((row >> 2) & 15);
        *(uint4*)&tile[row][pch * 8] = make_uint4(w[0], w[1], w[2], w[3]);
    }
    __syncthreads();

    #pragma unroll
    for (int q = 0; q < 4; ++q) {
        const int flat = q * 256 + t;
        const int row  = flat >> 4, ch = flat & 15;
        const int pch  = ch ^ ((row >> 2) & 15);
        uint4 val = *(const uint4*)&tile[row][pch * 8];
        *(uint4*)((char*)xT + (size_t)(m0 + row) * (KPAD * 2) + (size_t)(ct * 128 + ch * 8) * 2) = val;
    }
}

// ---------- kernel: local self-correlation partials ----------
// grid 512 = split(16) * b(8) * rowgroup(4). 256 thr: 16 rows x 16 col-strips(P=4).
// T14 async-stage: global loads 2 channels ahead into regs; ds_write right after the
// barrier; compute covers the load latency.
__global__ __launch_bounds__(256, 2) void k1a_corr(const float* __restrict__ x,
                                                   float* __restrict__ fpart)
{
    __shared__ float slab[2][20][68];
    const int bid   = blockIdx.x;
    const int split = bid & 15;
    const int b     = (bid >> 4) & 7;
    const int rg    = bid >> 7;
    const int y0    = rg * 16;
    const int t     = threadIdx.x;
    const int tc    = t & 15, tr = t >> 4;
    const int cs    = tc * 4;

    if (t < 160) {
        int buf = t / 80, rem = t % 80;
        int r = rem >> 2, cc = rem & 3;
        slab[buf][r][(cc < 2) ? cc : (64 + cc)] = 0.f;
    }

    float acc[25][4];
    #pragma unroll
    for (int s = 0; s < 25; ++s)
        #pragma unroll
        for (int p = 0; p < 4; ++p) acc[s][p] = 0.f;

    const float* xb = x + ((size_t)b * 1024 + split * 64) * 4096;

    const int r0 = t >> 4,         c40 = t & 15;
    const int y0r0 = y0 - 2 + r0;
    const int r1 = (t + 256) >> 4, c41 = t & 15;          // t<64 only
    const int y0r1 = y0 - 2 + r1;
    const bool has1 = (t < 64);

    #define K1A_LOAD(ch, VA, VB)                                                \
        {                                                                        \
            const float* s_ = xb + (size_t)(ch) * 4096;                          \
            VA = (y0r0 >= 0 && y0r0 < 64) ? *(const float4*)(s_ + y0r0 * 64 + c40 * 4) \
                                          : make_float4(0.f, 0.f, 0.f, 0.f);     \
            if (has1)                                                            \
                VB = (y0r1 >= 0 && y0r1 < 64) ? *(const float4*)(s_ + y0r1 * 64 + c41 * 4) \
                                              : make_float4(0.f, 0.f, 0.f, 0.f); \
        }
    #define K1A_WRITE(buf, VA, VB)                                               \
        {                                                                        \
            float2* d0 = (float2*)&slab[buf][r0][2 + c40 * 4];                   \
            d0[0] = make_float2(VA.x, VA.y);                                     \
            d0[1] = make_float2(VA.z, VA.w);                                     \
            if (has1) {                                                          \
                float2* d1 = (float2*)&slab[buf][r1][2 + c41 * 4];               \
                d1[0] = make_float2(VB.x, VB.y);                                 \
                d1[1] = make_float2(VB.z, VB.w);                                 \
            }                                                                    \
        }
    #define K1A_COMPUTE(buf)                                                     \
        {                                                                        \
            const float* base = &slab[buf][tr][cs];                              \
            float ctr[4], wf[8];                                                 \
            {                                                                    \
                const float4* pr = (const float4*)(base + 2 * 68);               \
                float4 a = pr[0], b4 = pr[1];                                    \
                wf[0]=a.x; wf[1]=a.y; wf[2]=a.z; wf[3]=a.w;                      \
                wf[4]=b4.x; wf[5]=b4.y; wf[6]=b4.z; wf[7]=b4.w;                  \
                ctr[0]=wf[2]; ctr[1]=wf[3]; ctr[2]=wf[4]; ctr[3]=wf[5];          \
                _Pragma("unroll")                                                \
                for (int dx = -2; dx <= 2; ++dx)                                 \
                    _Pragma("unroll")                                            \
                    for (int p = 0; p < 4; ++p)                                  \
                        acc[10 + dx + 2][p] += wf[p + 2 + dx] * ctr[p];          \
            }                                                                    \
            _Pragma("unroll")                                                    \
            for (int r = 0; r < 5; ++r) {                                        \
                if (r == 2) continue;                                            \
                const float4* pr = (const float4*)(base + r * 68);               \
                float4 a = pr[0], b4 = pr[1];                                    \
                wf[0]=a.x; wf[1]=a.y; wf[2]=a.z; wf[3]=a.w;                      \
                wf[4]=b4.x; wf[5]=b4.y; wf[6]=b4.z; wf[7]=b4.w;                  \
                _Pragma("unroll")                                                \
                for (int dx = -2; dx <= 2; ++dx)                                 \
                    _Pragma("unroll")                                            \
                    for (int p = 0; p < 4; ++p)                                  \
                        acc[r * 5 + dx + 2][p] += wf[p + 2 + dx] * ctr[p];       \
            }                                                                    \
        }

    float4 Sa0, Sa1, Sb0, Sb1;
    K1A_LOAD(0, Sa0, Sa1)
    K1A_LOAD(1, Sb0, Sb1)
    K1A_WRITE(0, Sa0, Sa1)
    K1A_LOAD(2, Sa0, Sa1)
    __syncthreads();

    for (int i = 0; i < 64; i += 2) {
        K1A_WRITE(1, Sb0, Sb1)
        K1A_LOAD(min(i + 3, 63), Sb0, Sb1)
        K1A_COMPUTE(0)
        __syncthreads();
        K1A_WRITE(0, Sa0, Sa1)
        K1A_LOAD(min(i + 4, 63), Sa0, Sa1)
        K1A_COMPUTE(1)
        __syncthreads();
    }
    #undef K1A_LOAD
    #undef K1A_WRITE
    #undef K1A_COMPUTE

    const int mbase = b * 4096 + (y0 + tr) * 64 + cs;
    #pragma unroll
    for (int s = 0; s < 25; ++s) {
        *(float4*)(fpart + (size_t)(split * 25 + s) * 32768 + mbase) =
            make_float4(acc[s][0], acc[s][1], acc[s][2], acc[s][3]);
    }
}

// ---------- kernel: reduce 16 partials, L2-normalize, write bf16 into xT[m][1024..1088) ----------
__global__ void k1b_norm(const float* __restrict__ fpart, unsigned short* __restrict__ xT)
{
    const int m = blockIdx.x * 256 + threadIdx.x;
    float f[25];
    #pragma unroll
    for (int s = 0; s < 25; ++s) {
        float v = 0.f;
        #pragma unroll
        for (int sp = 0; sp < 16; ++sp)
            v += fpart[(size_t)(sp * 25 + s) * 32768 + m];
        f[s] = v;
    }
    float ss = 1e-6f;
    #pragma unroll
    for (int s = 0; s < 25; ++s) ss += f[s] * f[s];
    const float inv = 1.f / sqrtf(ss);

    unsigned int w[16];
    #pragma unroll
    for (int q = 0; q < 16; ++q) w[q] = 0u;
    #pragma unroll
    for (int s = 0; s < 25; ++s) {
        unsigned int h = f2bf(f[s] * inv);
        w[s >> 1] |= h << ((s & 1) * 16);
    }
    uint4* dst = (uint4*)((char*)xT + (size_t)m * (KPAD * 2) + 2048);
    dst[0] = make_uint4(w[0],  w[1],  w[2],  w[3]);
    dst[1] = make_uint4(w[4],  w[5],  w[6],  w[7]);
    dst[2] = make_uint4(w[8],  w[9],  w[10], w[11]);
    dst[3] = make_uint4(w[12], w[13], w[14], w[15]);
    uint4 z = make_uint4(0u, 0u, 0u, 0u);
    dst[4] = z; dst[5] = z; dst[6] = z; dst[7] = z;
}

// ---------- kernel: 256x256 8-phase GEMM, deep prefetch v2 (race-audited) ----------
// BM=BN=256, BK=64, 8 waves (2M x 4N), per-wave 128x64, 16x16x32 bf16 MFMA.
// LDS 128KB: A/B double-buffered [2][256][64] with 8-slot XOR swizzle (conflicts = 0).
// Fragment->region map (the round-5 bug): for wave wn in {0,1}, BOTH b0 and b1 live in
// B rows [0:128); for wm, both a0/a1 live in A rows [wm*128, wm*128+128). Hence a
// region of the CURRENT buffer may only be re-staged (for t+2) after BOTH its
// fragment reads completed:
//   ph1: read a0,b0              | bar lgkm0 | MM(a0,b0)
//   ph2: read a1,b1              | bar lgkm0 | MM(a0,b1)    [all A,B reads done at close]
//   ph3: stage B-lo+B-hi(t+2)    | bar       | MM(a1,b0)    [B reads done ph2-close]
//   ph4: stage A-lo+A-hi(t+2)    | bar       | MM(a1,b1); vmcnt(8)   [A done ph2-close]
// Invariant entering tile t: t+1's 8 loads outstanding (staged 4-6 phases earlier,
// ~1000+ cyc >> 900 cyc HBM latency). ph4's vmcnt(8) drains exactly t+1.
__global__ __launch_bounds__(512, 2) void kgemm(const unsigned short* __restrict__ xT,
                                                const unsigned short* __restrict__ Wb,
                                                const float* __restrict__ bias,
                                                float* __restrict__ out)
{
    __shared__ unsigned short LA[2][256][64];   // 64KB
    __shared__ unsigned short LB[2][256][64];   // 64KB

    const int bid = blockIdx.x;                 // 512 blocks
    const int wg  = (bid & 7) * 64 + (bid >> 3);
    const int mt  = wg >> 2, nt = wg & 3;
    const int m0  = mt * 256, n0 = nt * 256;
    const int t   = threadIdx.x;
    const int l   = t & 63, w = t >> 6;
    const int lr  = l & 15, kq = l >> 4;
    const int wm  = w >> 2, wn = w & 3;

    const int sr = l >> 3;
    const int sp = (l & 7) ^ sr;
    const unsigned short* gA = xT + (size_t)(m0 + w * 8 + sr) * KPAD + sp * 8;
    const unsigned short* gB = Wb + (size_t)(n0 + w * 8 + sr) * KPAD + sp * 8;

    // half: 0 = A rows[0:128), 1 = A[128:256), 2 = B[0:128), 3 = B[128:256)
    auto STAGE = [&](int tt, int half) {
        if ((unsigned)tt >= NT) return;
        const int db = tt & 1;
        const size_t ko = (size_t)tt * 64;
        if (half < 2) {
            const unsigned short* g = gA + (size_t)(half * 128) * KPAD + ko;
            __builtin_amdgcn_global_load_lds((const void*)g,
                (void*)&LA[db][half * 128 + w * 8][0], 16, 0, 0);
            __builtin_amdgcn_global_load_lds((const void*)(g + (size_t)64 * KPAD),
                (void*)&LA[db][half * 128 + 64 + w * 8][0], 16, 0, 0);
        } else {
            const int hb = half - 2;
            const unsigned short* g = gB + (size_t)(hb * 128) * KPAD + ko;
            __builtin_amdgcn_global_load_lds((const void*)g,
                (void*)&LB[db][hb * 128 + w * 8][0], 16, 0, 0);
            __builtin_amdgcn_global_load_lds((const void*)(g + (size_t)64 * KPAD),
                (void*)&LB[db][hb * 128 + 64 + w * 8][0], 16, 0, 0);
        }
    };

    f32x4 zero = {0.f, 0.f, 0.f, 0.f};
    f32x4 acc[8][4];
    #pragma unroll
    for (int i = 0; i < 8; ++i)
        #pragma unroll
        for (int j = 0; j < 4; ++j) acc[i][j] = zero;

    bf16x8 a0[4][2], a1[4][2], b0[2][2], b1[2][2];

    #define LDA(dst, dbuf, ih)                                                   \
        _Pragma("unroll")                                                        \
        for (int i = 0; i < 4; ++i) {                                            \
            _Pragma("unroll")                                                    \
            for (int ks = 0; ks < 2; ++ks) {                                     \
                const int row = wm * 128 + ((ih) * 4 + i) * 16 + lr;             \
                const int slot = (ks * 4 + kq) ^ (row & 7);                      \
                dst[i][ks] = *(const bf16x8*)&LA[dbuf][row][slot * 8];           \
            }                                                                    \
        }
    #define LDB(dst, dbuf, jh)                                                   \
        _Pragma("unroll")                                                        \
        for (int j = 0; j < 2; ++j) {                                            \
            _Pragma("unroll")                                                    \
            for (int ks = 0; ks < 2; ++ks) {                                     \
                const int row = wn * 64 + ((jh) * 2 + j) * 16 + lr;              \
                const int slot = (ks * 4 + kq) ^ (row & 7);                      \
                dst[j][ks] = *(const bf16x8*)&LB[dbuf][row][slot * 8];           \
            }                                                                    \
        }
    #define MM(A, B, i0, j0)                                                     \
        _Pragma("unroll")                                                        \
        for (int ks = 0; ks < 2; ++ks) {                                         \
            _Pragma("unroll")                                                    \
            for (int i = 0; i < 4; ++i) {                                        \
                _Pragma("unroll")                                                \
                for (int j = 0; j < 2; ++j)                                      \
                    acc[(i0) + i][(j0) + j] = __builtin_amdgcn_mfma_f32_16x16x32_bf16( \
                        A[i][ks], B[j][ks], acc[(i0) + i][(j0) + j], 0, 0, 0);   \
            }                                                                    \
        }
    #define BAR()   asm volatile("s_barrier" ::: "memory");
    #define LGKM0() asm volatile("s_waitcnt lgkmcnt(0)" ::: "memory");           \
                    __builtin_amdgcn_sched_barrier(0);

    // prologue: stage tiles 0 and 1 fully (16 loads); vmcnt(8) drains tile 0.
    STAGE(0, 0); STAGE(0, 1); STAGE(0, 2); STAGE(0, 3);
    STAGE(1, 0); STAGE(1, 1); STAGE(1, 2); STAGE(1, 3);
    asm volatile("s_waitcnt vmcnt(8)" ::: "memory");
    BAR()

    for (int tt = 0; tt < NT; ++tt) {
        const int db = tt & 1;
        // ---- ph1: read a0,b0; MM(a0,b0)
        LDA(a0, db, 0)
        LDB(b0, db, 0)
        BAR()
        LGKM0()
        __builtin_amdgcn_s_setprio(1);
        MM(a0, b0, 0, 0)
        __builtin_amdgcn_s_setprio(0);
        BAR()
        // ---- ph2: read a1,b1; MM(a0,b1)   [after this phase ALL buf-db reads done]
        LDA(a1, db, 1)
        LDB(b1, db, 1)
        BAR()
        LGKM0()
        __builtin_amdgcn_s_setprio(1);
        MM(a0, b1, 0, 2)
        __builtin_amdgcn_s_setprio(0);
        BAR()
        // ---- ph3: stage B-lo+B-hi(t+2) [B reads done ph2-close]; MM(a1,b0)
        STAGE(tt + 2, 2);
        STAGE(tt + 2, 3);
        BAR()
        LGKM0()
        __builtin_amdgcn_s_setprio(1);
        MM(a1, b0, 4, 0)
        __builtin_amdgcn_s_setprio(0);
        BAR()
        // ---- ph4: stage A-lo+A-hi(t+2); MM(a1,b1); drain tile t+1's 8 loads
        STAGE(tt + 2, 0);
        STAGE(tt + 2, 1);
        BAR()
        LGKM0()
        __builtin_amdgcn_s_setprio(1);
        MM(a1, b1, 4, 2)
        __builtin_amdgcn_s_setprio(0);
        if (tt + 2 < NT) {
            asm volatile("s_waitcnt vmcnt(8)" ::: "memory");
        } else {
            asm volatile("s_waitcnt vmcnt(0)" ::: "memory");
        }
        BAR()
    }

    // epilogue: D col = lane&15 (n), row = (lane>>4)*4 + reg (m)
    const int bb = m0 >> 12;
    const int ms = (m0 & 4095) + wm * 128 + kq * 4;
    #pragma unroll
    for (int j = 0; j < 4; ++j) {
        const int n = n0 + wn * 64 + j * 16 + lr;
        const float bv = bias[n];
        float* ob = out + (size_t)bb * 4194304 + (size_t)n * 4096 + ms;
        #pragma unroll
        for (int i = 0; i < 8; ++i) {
            f32x4 v = acc[i][j];
            float4 o = make_float4(fmaxf(v[0] + bv, 0.f), fmaxf(v[1] + bv, 0.f),
                                   fmaxf(v[2] + bv, 0.f), fmaxf(v[3] + bv, 0.f));
            *(float4*)(ob + i * 16) = o;
        }
    }
    #undef LDA
    #undef LDB
    #undef MM
    #undef BAR
    #undef LGKM0
}

// ---------- launch ----------
extern "C" void kernel_launch(void* const* d_in, const int* in_sizes, int n_in,
                              void* d_out, int out_size, void* d_ws, size_t ws_size,
                              hipStream_t stream)
{
    const float* x    = (const float*)d_in[0];
    const float* W    = (const float*)d_in[1];
    const float* bias = (const float*)d_in[2];
    float* out        = (float*)d_out;

    char* ws = (char*)d_ws;
    // ws: xT 32768*1088*2 = 71,303,168 B ; Wb 1088*1024*2 = 2,228,224 B (total 73.5MB)
    // fpart (16*25*32768*4 = 52.4MB) lives in d_out scratch; kgemm overwrites all of
    // d_out afterwards, so timing replays stay deterministic.
    unsigned short* xT = (unsigned short*)ws;
    unsigned short* Wb = (unsigned short*)(ws + 71303168);
    float* fpart       = (float*)d_out;

    kWb_conv<<<1024, 256, 0, stream>>>(W, Wb);
    kT_conv <<<4096, 256, 0, stream>>>(x, xT);
    k1a_corr<<<512,  256, 0, stream>>>(x, fpart);
    k1b_norm<<<128,  256, 0, stream>>>(fpart, xT);
    kgemm   <<<512,  512, 0, stream>>>(xT, Wb, bias, out);
}